// Round 1
// baseline (934.233 us; speedup 1.0000x reference)
//
#include <hip/hip_runtime.h>
#include <hip/hip_bf16.h>
#include <math.h>

#define N_TOK 2048
#define DIM   1024
#define NE    16
#define NH    2048
#define NO    1024

typedef __attribute__((ext_vector_type(8))) short short8;
typedef __attribute__((ext_vector_type(4))) float f32x4;

__device__ __forceinline__ unsigned short f2bf(float f) {
  union { float f; unsigned u; } v; v.f = f;
  unsigned r = v.u + 0x7FFFu + ((v.u >> 16) & 1u);  // round-to-nearest-even
  return (unsigned short)(r >> 16);
}

// ---------------- Router: fp32 in, double accum, top-2 + renorm ----------------
__global__ __launch_bounds__(256) void router_kernel(
    const float* __restrict__ z, const float* __restrict__ rw,
    const float* __restrict__ rb, int* __restrict__ counts,
    int* __restrict__ list, float* __restrict__ tkw) {
  const int n = blockIdx.x;
  const int t = threadIdx.x;
  const int e = t >> 4, sub = t & 15;          // 16 threads per expert
  const float* zr = z + (size_t)n * DIM;
  const float* wr = rw + (size_t)e * DIM;
  double acc = 0.0;
#pragma unroll
  for (int i = 0; i < 16; ++i) {
    const int d = i * 64 + sub * 4;
    const float4 zv = *(const float4*)(zr + d);
    const float4 wv = *(const float4*)(wr + d);
    acc += (double)zv.x * wv.x + (double)zv.y * wv.y
         + (double)zv.z * wv.z + (double)zv.w * wv.w;
  }
  acc += __shfl_xor(acc, 8, 16);
  acc += __shfl_xor(acc, 4, 16);
  acc += __shfl_xor(acc, 2, 16);
  acc += __shfl_xor(acc, 1, 16);
  __shared__ double logits[NE];
  if (sub == 0) logits[e] = acc + (double)rb[e];
  __syncthreads();
  if (t == 0) {
    int i0 = -1, i1 = -1; double v0 = -1e300, v1 = -1e300;
    for (int i = 0; i < NE; ++i) {          // strict > : ties pick lowest index (matches lax.top_k)
      const double v = logits[i];
      if (v > v0) { v1 = v0; i1 = i0; v0 = v; i0 = i; }
      else if (v > v1) { v1 = v; i1 = i; }
    }
    const double w0 = 1.0 / (1.0 + exp(v1 - v0));   // p0/(p0+p1), softmax Z cancels
    tkw[n * 2 + 0] = (float)w0;
    tkw[n * 2 + 1] = (float)(1.0 - w0);
    const int p0 = atomicAdd(&counts[i0], 1); list[i0 * N_TOK + p0] = n * 2;
    const int p1 = atomicAdd(&counts[i1], 1); list[i1 * N_TOK + p1] = n * 2 + 1;
  }
}

// ---------------- GEMM1: h[slot] = gelu(z[tok] @ w1[e]^T + b1[e]) -> bf16 ----------------
#define BM 128
#define BN 128
#define BK 64
#define LDK 72   // +8 bf16 pad (16B): stride 144B -> 2-way bank alias (free, m136)

__global__ __launch_bounds__(256) void gemm1_kernel(
    const float* __restrict__ z, const float* __restrict__ w1,
    const float* __restrict__ b1, const int* __restrict__ counts,
    const int* __restrict__ list, unsigned short* __restrict__ h) {
  const int bid = blockIdx.x;
  const int e  = bid >> 8;          // 16 nt * 16 mt per expert
  const int nt = (bid >> 4) & 15;
  const int mt = bid & 15;
  const int ne = counts[e];
  if (mt * BM >= ne) return;
  const int t = threadIdx.x;

  __shared__ unsigned short As[BM][LDK];
  __shared__ unsigned short Bs[BN][LDK];
  __shared__ int ent[BM];
  if (t < BM) {
    const int idx = mt * BM + t;
    ent[t] = (idx < ne) ? list[e * N_TOK + idx] : -1;
  }
  __syncthreads();

  const int lane = t & 63, wave = t >> 6;
  const int wm = (wave & 1) * 64, wn = (wave >> 1) * 64;
  const int l15 = lane & 15, q8 = (lane >> 4) * 8;

  f32x4 acc[4][4];
#pragma unroll
  for (int i = 0; i < 4; ++i)
#pragma unroll
    for (int j = 0; j < 4; ++j) acc[i][j] = (f32x4){0.f, 0.f, 0.f, 0.f};

  const int r0 = t >> 4;            // staging: 16 rows/pass, 8 passes
  const int c0 = (t & 15) * 4;      // 64-wide K slab, float4 per thread

  const float* aptr[8];
  const float* bptr[8];
  const float* bbase = w1 + ((size_t)e * NH + (size_t)nt * BN) * DIM;
#pragma unroll
  for (int p = 0; p < 8; ++p) {
    const int row = r0 + p * 16;
    const int en = ent[row];
    aptr[p] = z + (size_t)(en >= 0 ? (en >> 1) : 0) * DIM;
    bptr[p] = bbase + (size_t)row * DIM;
  }

  for (int k0 = 0; k0 < DIM; k0 += BK) {
#pragma unroll
    for (int p = 0; p < 8; ++p) {
      const int row = r0 + p * 16;
      const float4 v = *(const float4*)(aptr[p] + k0 + c0);
      ushort4 s; s.x = f2bf(v.x); s.y = f2bf(v.y); s.z = f2bf(v.z); s.w = f2bf(v.w);
      *(ushort4*)&As[row][c0] = s;
      const float4 w = *(const float4*)(bptr[p] + k0 + c0);
      ushort4 sw; sw.x = f2bf(w.x); sw.y = f2bf(w.y); sw.z = f2bf(w.z); sw.w = f2bf(w.w);
      *(ushort4*)&Bs[row][c0] = sw;
    }
    __syncthreads();
#pragma unroll
    for (int kk = 0; kk < BK; kk += 32) {
      short8 a[4], b[4];
#pragma unroll
      for (int i = 0; i < 4; ++i) a[i] = *(const short8*)&As[wm + i * 16 + l15][kk + q8];
#pragma unroll
      for (int j = 0; j < 4; ++j) b[j] = *(const short8*)&Bs[wn + j * 16 + l15][kk + q8];
#pragma unroll
      for (int i = 0; i < 4; ++i)
#pragma unroll
        for (int j = 0; j < 4; ++j)
          acc[i][j] = __builtin_amdgcn_mfma_f32_16x16x32_bf16(a[i], b[j], acc[i][j], 0, 0, 0);
    }
    __syncthreads();
  }

  const int r4 = (lane >> 4) * 4;   // C/D: col=lane&15, row=(lane>>4)*4+reg
#pragma unroll
  for (int i = 0; i < 4; ++i) {
#pragma unroll
    for (int reg = 0; reg < 4; ++reg) {
      const int row = wm + i * 16 + r4 + reg;
      const int en = ent[row];
      if (en < 0) continue;
      unsigned short* hrow = h + (size_t)en * NH;
#pragma unroll
      for (int j = 0; j < 4; ++j) {
        const int col = nt * BN + wn + j * 16 + l15;
        float v = acc[i][j][reg] + b1[e * NH + col];
        v = 0.5f * v * (1.0f + erff(v * 0.70710678118654752f));   // exact gelu
        hrow[col] = f2bf(v);
      }
    }
  }
}

// ---------------- GEMM2: contrib[slot] = h[slot] @ w2[e]^T + b2[e] (fp32) ----------------
__global__ __launch_bounds__(256) void gemm2_kernel(
    const unsigned short* __restrict__ h, const float* __restrict__ w2,
    const float* __restrict__ b2, const int* __restrict__ counts,
    const int* __restrict__ list, float* __restrict__ contrib) {
  const int bid = blockIdx.x;
  const int e  = bid >> 7;          // 8 nt * 16 mt per expert
  const int nt = (bid >> 4) & 7;
  const int mt = bid & 15;
  const int ne = counts[e];
  if (mt * BM >= ne) return;
  const int t = threadIdx.x;

  __shared__ unsigned short As[BM][LDK];
  __shared__ unsigned short Bs[BN][LDK];
  __shared__ int ent[BM];
  if (t < BM) {
    const int idx = mt * BM + t;
    ent[t] = (idx < ne) ? list[e * N_TOK + idx] : -1;
  }
  __syncthreads();

  const int lane = t & 63, wave = t >> 6;
  const int wm = (wave & 1) * 64, wn = (wave >> 1) * 64;
  const int l15 = lane & 15, q8 = (lane >> 4) * 8;

  f32x4 acc[4][4];
#pragma unroll
  for (int i = 0; i < 4; ++i)
#pragma unroll
    for (int j = 0; j < 4; ++j) acc[i][j] = (f32x4){0.f, 0.f, 0.f, 0.f};

  // A staging: bf16 passthrough, 16B/thread: 32 rows/pass * 4 passes
  const int ar = t >> 3;            // 0..31
  const int ac = (t & 7) * 8;       // bf16 col, 16B steps
  const unsigned short* aptr[4];
#pragma unroll
  for (int p = 0; p < 4; ++p) {
    const int row = ar + p * 32;
    const int en = ent[row];
    aptr[p] = h + (size_t)(en >= 0 ? en : 0) * NH;
  }
  // B staging: fp32 w2 -> bf16
  const int r0 = t >> 4;
  const int c0 = (t & 15) * 4;
  const float* bptr[8];
  const float* bbase = w2 + ((size_t)e * NO + (size_t)nt * BN) * NH;
#pragma unroll
  for (int p = 0; p < 8; ++p) bptr[p] = bbase + (size_t)(r0 + p * 16) * NH;

  for (int k0 = 0; k0 < NH; k0 += BK) {
#pragma unroll
    for (int p = 0; p < 4; ++p) {
      const int row = ar + p * 32;
      const float4 v = *(const float4*)(aptr[p] + k0 + ac);   // 8 bf16 raw bits
      *(float4*)&As[row][ac] = v;
    }
#pragma unroll
    for (int p = 0; p < 8; ++p) {
      const int row = r0 + p * 16;
      const float4 w = *(const float4*)(bptr[p] + k0 + c0);
      ushort4 sw; sw.x = f2bf(w.x); sw.y = f2bf(w.y); sw.z = f2bf(w.z); sw.w = f2bf(w.w);
      *(ushort4*)&Bs[row][c0] = sw;
    }
    __syncthreads();
#pragma unroll
    for (int kk = 0; kk < BK; kk += 32) {
      short8 a[4], b[4];
#pragma unroll
      for (int i = 0; i < 4; ++i) a[i] = *(const short8*)&As[wm + i * 16 + l15][kk + q8];
#pragma unroll
      for (int j = 0; j < 4; ++j) b[j] = *(const short8*)&Bs[wn + j * 16 + l15][kk + q8];
#pragma unroll
      for (int i = 0; i < 4; ++i)
#pragma unroll
        for (int j = 0; j < 4; ++j)
          acc[i][j] = __builtin_amdgcn_mfma_f32_16x16x32_bf16(a[i], b[j], acc[i][j], 0, 0, 0);
    }
    __syncthreads();
  }

  const int r4 = (lane >> 4) * 4;
#pragma unroll
  for (int i = 0; i < 4; ++i) {
#pragma unroll
    for (int reg = 0; reg < 4; ++reg) {
      const int row = wm + i * 16 + r4 + reg;
      const int en = ent[row];
      if (en < 0) continue;
      float* crow = contrib + (size_t)en * NO;
#pragma unroll
      for (int j = 0; j < 4; ++j) {
        const int col = nt * BN + wn + j * 16 + l15;
        crow[col] = acc[i][j][reg] + b2[e * NO + col];
      }
    }
  }
}

// ---------------- Combine: out[n] = w0*contrib[2n] + w1*contrib[2n+1] ----------------
__global__ __launch_bounds__(256) void combine_kernel(
    const float* __restrict__ contrib, const float* __restrict__ tkw,
    float* __restrict__ out) {
  const int gid = blockIdx.x * 256 + threadIdx.x;   // N_TOK * (NO/4) threads
  const int n = gid >> 8;
  const int c = (gid & 255) * 4;
  const float w0 = tkw[n * 2], w1 = tkw[n * 2 + 1];
  const float4 a = *(const float4*)(contrib + (size_t)(n * 2) * NO + c);
  const float4 b = *(const float4*)(contrib + (size_t)(n * 2 + 1) * NO + c);
  float4 o;
  o.x = w0 * a.x + w1 * b.x; o.y = w0 * a.y + w1 * b.y;
  o.z = w0 * a.z + w1 * b.z; o.w = w0 * a.w + w1 * b.w;
  *(float4*)(out + (size_t)n * NO + c) = o;
}

extern "C" void kernel_launch(void* const* d_in, const int* in_sizes, int n_in,
                              void* d_out, int out_size, void* d_ws, size_t ws_size,
                              hipStream_t stream) {
  const float* z  = (const float*)d_in[0];
  const float* rw = (const float*)d_in[1];
  const float* rb = (const float*)d_in[2];
  const float* w1 = (const float*)d_in[3];
  const float* b1 = (const float*)d_in[4];
  const float* w2 = (const float*)d_in[5];
  const float* b2 = (const float*)d_in[6];
  float* out = (float*)d_out;

  char* ws = (char*)d_ws;
  int*   counts = (int*)ws;                                   // 64 B (zeroed below)
  int*   list   = (int*)(ws + 256);                           // 16*2048*4 = 128 KB
  float* tkw    = (float*)(ws + 256 + 131072);                // 16 KB
  unsigned short* h = (unsigned short*)(ws + 262144);         // 4096*2048 bf16 = 16 MB
  float* contrib = (float*)(ws + 262144 + 16777216);          // 4096*1024 f32 = 16 MB

  hipMemsetAsync(counts, 0, NE * sizeof(int), stream);
  router_kernel<<<N_TOK, 256, 0, stream>>>(z, rw, rb, counts, list, tkw);
  gemm1_kernel<<<NE * 16 * 16, 256, 0, stream>>>(z, w1, b1, counts, list, h);
  gemm2_kernel<<<NE * 16 * 8, 256, 0, stream>>>(h, w2, b2, counts, list, contrib);
  combine_kernel<<<(N_TOK * (NO / 4)) / 256, 256, 0, stream>>>(contrib, tkw, out);
}